// Round 25
// baseline (350.571 us; speedup 1.0000x reference)
//
#include <hip/hip_runtime.h>
#include <math.h>

typedef float  f32x4  __attribute__((ext_vector_type(4)));
typedef float  f32x2  __attribute__((ext_vector_type(2)));

#define DIM   1024
#define RANK  256
#define NROWS 16
#define NT    512
#define NWAVE 8
#define TOTAL_ROWS 4096
#define OUT_HALF (TOTAL_ROWS*DIM)

// LDS byte layout (86.6 KB) — fp8 A-operands, B-frags stream global->VGPR.
#define VS_OFF    0           // fp8[16][1024] swizzled: v / gamma / v'  (16384)
#define H2_OFF    16384       // fp8[16][256] swizzled                    (4096)
#define XS_OFF    20480       // float[16][1024] thread-private x state  (65536)
#define WS_OFF    86016       // float[16][8]
#define SG_OFF    86528       // float[16]
#define SMEM_BYTES 86592

static constexpr double XI  = 0.1786178958448091;
static constexpr double LAM = -0.2123418310626054;
static constexpr double CHI = -0.0662645826698185;

// ---- fp8 e4m3fn converters (software, RNE, subnormal-correct) ----
__device__ __forceinline__ unsigned f2e4m3(float f) {
    unsigned u = __builtin_bit_cast(unsigned, f);
    const unsigned s = (u >> 24) & 0x80u;
    unsigned a = u & 0x7FFFFFFFu;
    const float af = __builtin_bit_cast(float, a);
    if (af < 0.015625f) {                       // subnormal: round(af*512) in 0..8
        return s | (unsigned)(int)rintf(af * 512.0f);
    }
    a += 0x7FFFFu + ((a >> 20) & 1u);           // RNE into 3-bit mantissa
    if (a > 0x43E00000u) return s | 0x7Eu;      // clamp to 448
    const unsigned e = (a >> 23) & 0xFFu;       // >= 121
    return s | ((e - 120u) << 3) | ((a >> 20) & 7u);
}
__device__ __forceinline__ float e4m32f(unsigned b) {
    const unsigned e = (b >> 3) & 0xFu, m = b & 7u;
    const float mag = (e != 0)
        ? __builtin_bit_cast(float, ((e + 120u) << 23) | (m << 20))
        : (float)m * 0.001953125f;
    return (b & 0x80u) ? -mag : mag;
}

__device__ __forceinline__ unsigned short f2bf(float f) {
    unsigned u = __builtin_bit_cast(unsigned, f);
    u += 0x7FFFu + ((u >> 16) & 1u);
    return (unsigned short)(u >> 16);
}

// swizzles: byte ^= (row&7)<<3 (8B-granular for ds_read_b64 A-frags)
__device__ __forceinline__ int vs_addr(int m, int k) {   // k = byte col (1B/elem)
    return VS_OFF + ((m * 1024 + k) ^ ((m & 7) << 3));
}
__device__ __forceinline__ int h2_addr(int m, int k) {
    return H2_OFF + ((m * 256 + k) ^ ((m & 7) << 3));
}

// ---- prep: pack 8*U, 8*W into fp8 e4m3 MFMA B-fragment order.
// U slot = kt*16+nt (kt<32,nt<16); W slot = 512 + kt*64+nt (kt<8,nt<64)
// B-frag 16x16x32 fp8: lane l holds B[k = kt*32 + (l>>4)*8 + j][n = nt*16 + (l&15)]
// byte j of the i64 = element j (same ordering convention as the bf16 frags).
__global__ __launch_bounds__(256)
void prep_pack(const float* __restrict__ U, const float* __restrict__ Wm,
               long* __restrict__ pk8)
{
    const int tid  = blockIdx.x * 256 + threadIdx.x;   // 0..65535
    const int lane = tid & 63;
    const int frag = tid >> 6;                          // 0..1023
    unsigned long long o = 0;
    if (frag < 512) {
        const int kt = frag >> 4, nt = frag & 15;
        const int krow = kt * 32 + (lane >> 4) * 8;
        const int n    = nt * 16 + (lane & 15);
        #pragma unroll
        for (int j = 0; j < 8; ++j)
            o |= (unsigned long long)f2e4m3(8.0f * U[(krow + j) * RANK + n]) << (8 * j);
    } else {
        const int f = frag - 512;
        const int kt = f >> 6, nt = f & 63;
        const int krow = kt * 32 + (lane >> 4) * 8;
        const int n    = nt * 16 + (lane & 15);
        #pragma unroll
        for (int j = 0; j < 8; ++j)
            o |= (unsigned long long)f2e4m3(8.0f * Wm[(krow + j) * DIM + n]) << (8 * j);
    }
    pk8[frag * 64 + lane] = (long)o;
}

__global__ __launch_bounds__(NT)
void omelyan_mfma(const float* __restrict__ x_in,
                  const float* __restrict__ v_in,
                  const float* __restrict__ force,
                  const float* __restrict__ Vw,
                  const int* __restrict__ steps_p,
                  const long* __restrict__ pk8,
                  float* __restrict__ out)
{
    extern __shared__ char smem[];
    float* wsums = (float*)(smem + WS_OFF);
    float* sings = (float*)(smem + SG_OFF);
    float* xsp   = (float*)(smem + XS_OFF);   // [16][1024] f32, thread-private

    const int t    = threadIdx.x;        // 0..511
    const int lane = t & 63;
    const int w    = t >> 6;             // 0..7
    const int row0 = blockIdx.x * NROWS;
    const int nsteps = steps_p[0];

    const float dt = 0.01f;

    // per-thread register state: v only (elements d = 2t+j); x lives in LDS.
    float vr[NROWS][2];
    const f32x2 vw = *(const f32x2*)&Vw[2 * t];

    #pragma unroll
    for (int m = 0; m < NROWS; ++m) {
        const int base = (row0 + m) * DIM + 2 * t;
        const f32x2 xv = *(const f32x2*)&x_in[base];
        const f32x2 vv = *(const f32x2*)&v_in[base];
        vr[m][0] = vv[0]; vr[m][1] = vv[1];
        *(f32x2*)&xsp[m * 1024 + 2 * t] = xv;
        const unsigned short p = (unsigned short)(f2e4m3(vv[0]) | (f2e4m3(vv[1]) << 8));
        *(unsigned short*)(smem + vs_addr(m, 2 * t)) = p;
    }
    __syncthreads();

    #pragma unroll 1
    for (int step = 0; step < nsteps; ++step) {
        #pragma unroll 1
        for (int sub = 0; sub < 4; ++sub) {
            const float cdt = dt * (sub == 0 ? (float)XI :
                                    sub == 1 ? (float)CHI :
                                    sub == 2 ? (float)(1.0 - 2.0 * (CHI + XI)) :
                                               (float)CHI);
            const float ddt = dt * ((sub == 0 || sub == 3)
                                    ? (float)((1.0 - 2.0 * LAM) * 0.5)
                                    : (float)LAM);

            // ---- drift x (LDS RMW, thread-private) + r2 reduce -> wsums ----
            #pragma unroll
            for (int m = 0; m < NROWS; ++m) {
                f32x2 x2 = *(f32x2*)&xsp[m * 1024 + 2 * t];
                x2[0] = fmaf(cdt, vr[m][0], x2[0]);
                x2[1] = fmaf(cdt, vr[m][1], x2[1]);
                *(f32x2*)&xsp[m * 1024 + 2 * t] = x2;
                float s = fmaf(x2[0], x2[0], x2[1] * x2[1]);
                #pragma unroll
                for (int off = 32; off >= 1; off >>= 1) s += __shfl_xor(s, off, 64);
                if (lane == 0) wsums[m * NWAVE + w] = s;
            }
            __syncthreads();                 // b_A: vs(v') + wsums visible
            if (t < NROWS) {
                float r2 = 0.f;
                #pragma unroll
                for (int q = 0; q < NWAVE; ++q) r2 += wsums[t * NWAVE + q];
                sings[t] = 1.f + exp2f(-r2 * 1.4426950408889634f);
            }

            // ---- H: h = v @ U (fp8); wave owns nt {2w, 2w+1} ----
            // hacc = (v)·(8U) = 8h -> h = hacc/8; h2 stored = e4m3(16 h^2) = e4m3(hacc^2/4)
            {
                f32x4 h0 = {0.f,0.f,0.f,0.f}, h1 = {0.f,0.f,0.f,0.f};
                long bb[4][2];               // ring-4, 8 regs total
                #pragma unroll
                for (int d = 0; d < 4; ++d) {
                    bb[d][0] = pk8[(d * 16 + 2 * w + 0) * 64 + lane];
                    bb[d][1] = pk8[(d * 16 + 2 * w + 1) * 64 + lane];
                }
                #pragma unroll 4
                for (int ks = 0; ks < 32; ++ks) {
                    const long a = *(const long*)(smem + vs_addr(lane & 15, ks * 32 + (lane >> 4) * 8));
                    h0 = __builtin_amdgcn_mfma_f32_16x16x32_fp8_fp8(a, bb[ks & 3][0], h0, 0, 0, 0);
                    h1 = __builtin_amdgcn_mfma_f32_16x16x32_fp8_fp8(a, bb[ks & 3][1], h1, 0, 0, 0);
                    if (ks + 4 < 32) {
                        bb[ks & 3][0] = pk8[((ks + 4) * 16 + 2 * w + 0) * 64 + lane];
                        bb[ks & 3][1] = pk8[((ks + 4) * 16 + 2 * w + 1) * 64 + lane];
                    }
                }
                // h2 (fp8, swizzled); D: col=lane&15, row=(lane>>4)*4+r
                #pragma unroll
                for (int r = 0; r < 4; ++r) {
                    const int m = (lane >> 4) * 4 + r;
                    const int c = lane & 15;
                    *(unsigned char*)(smem + h2_addr(m, (2 * w + 0) * 16 + c)) =
                        (unsigned char)f2e4m3(h0[r] * h0[r] * 0.25f);
                    *(unsigned char*)(smem + h2_addr(m, (2 * w + 1) * 16 + c)) =
                        (unsigned char)f2e4m3(h1[r] * h1[r] * 0.25f);
                }
            }
            __syncthreads();                 // b_B: h2 visible

            // ---- G: gamma = h2 @ W (fp8); 4 passes, wave owns nt {p*16+2w,+1} ----
            // gacc = (16h^2)·(8W) = 128*gamma -> gamma = gacc/128
            {
                f32x4 g0 = {0.f,0.f,0.f,0.f}, g1 = {0.f,0.f,0.f,0.f};
                long bb[4][2];
                #pragma unroll
                for (int d = 0; d < 4; ++d) {
                    bb[d][0] = pk8[512 * 64 + (d * 64 + 2 * w + 0) * 64 + lane];
                    bb[d][1] = pk8[512 * 64 + (d * 64 + 2 * w + 1) * 64 + lane];
                }
                #pragma unroll 4
                for (int u = 0; u < 32; ++u) {
                    const int kk = u & 7;        // K-subtile
                    const int pass = u >> 3;     // n-pass
                    const long a = *(const long*)(smem + h2_addr(lane & 15, kk * 32 + (lane >> 4) * 8));
                    g0 = __builtin_amdgcn_mfma_f32_16x16x32_fp8_fp8(a, bb[u & 3][0], g0, 0, 0, 0);
                    g1 = __builtin_amdgcn_mfma_f32_16x16x32_fp8_fp8(a, bb[u & 3][1], g1, 0, 0, 0);
                    if (u + 4 < 32) {
                        const int u2 = u + 4;
                        const int kk2 = u2 & 7, p2 = u2 >> 3;
                        bb[u & 3][0] = pk8[512 * 64 + (kk2 * 64 + p2 * 16 + 2 * w + 0) * 64 + lane];
                        bb[u & 3][1] = pk8[512 * 64 + (kk2 * 64 + p2 * 16 + 2 * w + 1) * 64 + lane];
                    }
                    if (kk == 7) {               // end of pass: gamma (fp8) -> dead vs cells
                        #pragma unroll
                        for (int r = 0; r < 4; ++r) {
                            const int m = (lane >> 4) * 4 + r;
                            const int c = lane & 15;
                            *(unsigned char*)(smem + vs_addr(m, (pass * 16 + 2 * w + 0) * 16 + c)) =
                                (unsigned char)f2e4m3(g0[r] * 0.0078125f);
                            *(unsigned char*)(smem + vs_addr(m, (pass * 16 + 2 * w + 1) * 16 + c)) =
                                (unsigned char)f2e4m3(g1[r] * 0.0078125f);
                        }
                        g0 = (f32x4){0.f,0.f,0.f,0.f};
                        g1 = (f32x4){0.f,0.f,0.f,0.f};
                    }
                }
            }
            __syncthreads();                 // b_C: gamma visible

            // ---- kick: gamma from vs cells (fp8), x from xsp; write v' (fp8) ----
            #pragma unroll
            for (int m = 0; m < NROWS; ++m) {
                const f32x2 fm = *(const f32x2*)&force[(row0 + m) * DIM + 2 * t];
                const f32x2 x2 = *(const f32x2*)&xsp[m * 1024 + 2 * t];
                const unsigned gu = *(const unsigned short*)(smem + vs_addr(m, 2 * t));
                const float gL = e4m32f(gu & 0xFFu);
                const float gH = e4m32f((gu >> 8) & 0xFFu);
                const float sing = sings[m];
                unsigned pp = 0;
                #pragma unroll
                for (int j = 0; j < 2; ++j) {
                    const float g  = j ? gH : gL;
                    const float z  = x2[j] * vw[j];
                    const float e  = exp2f(z * 2.885390081777927f);   // e^(2z)
                    const float th = 1.f - 2.f / (e + 1.f);           // tanh(z)
                    const float gate = fmaf(0.1f, th, 1.f);
                    const float a = fm[j] - g * gate * sing;
                    vr[m][j] = fmaf(ddt, a, vr[m][j]);
                    pp |= f2e4m3(vr[m][j]) << (8 * j);
                }
                *(unsigned short*)(smem + vs_addr(m, 2 * t)) = (unsigned short)pp;
            }
            // next accel's b_A covers these vs writes
        } // sub

        // final drift: x += C5*dt*v  (LDS RMW, thread-private)
        const float c5dt = dt * (float)XI;
        #pragma unroll
        for (int m = 0; m < NROWS; ++m) {
            f32x2 x2 = *(f32x2*)&xsp[m * 1024 + 2 * t];
            x2[0] = fmaf(c5dt, vr[m][0], x2[0]);
            x2[1] = fmaf(c5dt, vr[m][1], x2[1]);
            *(f32x2*)&xsp[m * 1024 + 2 * t] = x2;
        }
    } // step

    __syncthreads();

    // ---- store (x, v) ----
    #pragma unroll
    for (int m = 0; m < NROWS; ++m) {
        const int base = (row0 + m) * DIM + 2 * t;
        const f32x2 x2 = *(const f32x2*)&xsp[m * 1024 + 2 * t];
        f32x2 vo; vo[0] = vr[m][0]; vo[1] = vr[m][1];
        *(f32x2*)&out[base] = x2;
        *(f32x2*)&out[OUT_HALF + base] = vo;
    }
}

extern "C" void kernel_launch(void* const* d_in, const int* in_sizes, int n_in,
                              void* d_out, int out_size, void* d_ws, size_t ws_size,
                              hipStream_t stream) {
    const float* x_in  = (const float*)d_in[0];
    const float* v_in  = (const float*)d_in[1];
    const float* force = (const float*)d_in[2];
    const float* Umat  = (const float*)d_in[3];
    const float* Wmat  = (const float*)d_in[4];
    const float* Vw    = (const float*)d_in[5];
    const int*   steps = (const int*)d_in[6];
    float* out = (float*)d_out;
    long* pk8 = (long*)d_ws;   // 512 KiB fp8 fragment stream

    (void)hipFuncSetAttribute((const void*)omelyan_mfma,
                              hipFuncAttributeMaxDynamicSharedMemorySize,
                              SMEM_BYTES);

    prep_pack<<<dim3(256), dim3(256), 0, stream>>>(Umat, Wmat, pk8);
    omelyan_mfma<<<dim3(TOTAL_ROWS / NROWS), dim3(NT), SMEM_BYTES, stream>>>(
        x_in, v_in, force, Vw, steps, pk8, out);
}

// Round 26
// 301.910 us; speedup vs baseline: 1.1612x; 1.1612x over previous
//
#include <hip/hip_runtime.h>
#include <math.h>

typedef float  f32x4  __attribute__((ext_vector_type(4)));
typedef float  f32x2  __attribute__((ext_vector_type(2)));
typedef long   i64x2  __attribute__((ext_vector_type(2)));

#define DIM   1024
#define RANK  256
#define NROWS 16
#define NT    512
#define NWAVE 8
#define TOTAL_ROWS 4096
#define OUT_HALF (TOTAL_ROWS*DIM)

// LDS byte layout (86.6 KB) — fp8 A-operands, B-frags stream global->VGPR.
#define VS_OFF    0           // fp8[16][1024] swizzled: v / gamma / v'  (16384)
#define H2_OFF    16384       // fp8[16][256] swizzled                    (4096)
#define XS_OFF    20480       // float[16][1024] thread-private x state  (65536)
#define WS_OFF    86016       // float[16][8]
#define SG_OFF    86528       // float[16]
#define SMEM_BYTES 86592

static constexpr double XI  = 0.1786178958448091;
static constexpr double LAM = -0.2123418310626054;
static constexpr double CHI = -0.0662645826698185;

// ---- fp8 e4m3fn converters (software, RNE, subnormal-correct) ----
__device__ __forceinline__ unsigned f2e4m3(float f) {
    unsigned u = __builtin_bit_cast(unsigned, f);
    const unsigned s = (u >> 24) & 0x80u;
    unsigned a = u & 0x7FFFFFFFu;
    const float af = __builtin_bit_cast(float, a);
    if (af < 0.015625f) {                       // subnormal: round(af*512) in 0..8
        return s | (unsigned)(int)rintf(af * 512.0f);
    }
    a += 0x7FFFFu + ((a >> 20) & 1u);           // RNE into 3-bit mantissa
    if (a > 0x43E00000u) return s | 0x7Eu;      // clamp to 448
    const unsigned e = (a >> 23) & 0xFFu;       // >= 121
    return s | ((e - 120u) << 3) | ((a >> 20) & 7u);
}
__device__ __forceinline__ float e4m32f(unsigned b) {
    const unsigned e = (b >> 3) & 0xFu, m = b & 7u;
    const float mag = (e != 0)
        ? __builtin_bit_cast(float, ((e + 120u) << 23) | (m << 20))
        : (float)m * 0.001953125f;
    return (b & 0x80u) ? -mag : mag;
}

// swizzles: byte ^= (row&7)<<3 (8B-granular, matches ds_read_b64 A-frags)
__device__ __forceinline__ int vs_addr(int m, int k) {   // k = byte col (1B/elem)
    return VS_OFF + ((m * 1024 + k) ^ ((m & 7) << 3));
}
__device__ __forceinline__ int h2_addr(int m, int k) {
    return H2_OFF + ((m * 256 + k) ^ ((m & 7) << 3));
}

// ---- prep: pack 8*U, 8*W (fp8 e4m3) into PAIRED-fragment slots: one
// 16B/lane load carries the wave's nt-pair {2w, 2w+1} -> halves VMEM
// transaction count vs one-frag-per-load (the R24/R25 invariant was
// ~50 cyc per VMEM instruction per CU, payload-size independent).
// H slot = ks*8 + w          (ks<32, w<8): lo=U-frag(ks, 2w), hi=U-frag(ks, 2w+1)
// G slot = 256 + (pass*8+kk)*8 + w : lo=W-frag(kk, pass*16+2w), hi=(.., +1)
// frag: lane l, byte j = B[k = kt*32 + (l>>4)*8 + j][n = nt*16 + (l&15)]
__global__ __launch_bounds__(256)
void prep_pack(const float* __restrict__ U, const float* __restrict__ Wm,
               long* __restrict__ pk8)
{
    const int tid  = blockIdx.x * 256 + threadIdx.x;   // 0..32767
    const int lane = tid & 63;
    const int slot = tid >> 6;                          // 0..511
    unsigned long long lo = 0, hi = 0;
    if (slot < 256) {
        const int ks = slot >> 3, w = slot & 7;
        const int krow = ks * 32 + (lane >> 4) * 8;
        const int n0 = (2 * w + 0) * 16 + (lane & 15);
        const int n1 = (2 * w + 1) * 16 + (lane & 15);
        #pragma unroll
        for (int j = 0; j < 8; ++j) {
            lo |= (unsigned long long)f2e4m3(8.0f * U[(krow + j) * RANK + n0]) << (8 * j);
            hi |= (unsigned long long)f2e4m3(8.0f * U[(krow + j) * RANK + n1]) << (8 * j);
        }
    } else {
        const int s2 = slot - 256;
        const int u = s2 >> 3, w = s2 & 7;
        const int pass = u >> 3, kk = u & 7;
        const int krow = kk * 32 + (lane >> 4) * 8;
        const int n0 = (pass * 16 + 2 * w + 0) * 16 + (lane & 15);
        const int n1 = (pass * 16 + 2 * w + 1) * 16 + (lane & 15);
        #pragma unroll
        for (int j = 0; j < 8; ++j) {
            lo |= (unsigned long long)f2e4m3(8.0f * Wm[(krow + j) * DIM + n0]) << (8 * j);
            hi |= (unsigned long long)f2e4m3(8.0f * Wm[(krow + j) * DIM + n1]) << (8 * j);
        }
    }
    pk8[(slot * 64 + lane) * 2 + 0] = (long)lo;
    pk8[(slot * 64 + lane) * 2 + 1] = (long)hi;
}

__global__ __launch_bounds__(NT)
void omelyan_mfma(const float* __restrict__ x_in,
                  const float* __restrict__ v_in,
                  const float* __restrict__ force,
                  const float* __restrict__ Vw,
                  const int* __restrict__ steps_p,
                  const long* __restrict__ pk8,
                  float* __restrict__ out)
{
    extern __shared__ char smem[];
    float* wsums = (float*)(smem + WS_OFF);
    float* sings = (float*)(smem + SG_OFF);
    float* xsp   = (float*)(smem + XS_OFF);   // [16][1024] f32, thread-private
    const i64x2* pkv = (const i64x2*)pk8;

    const int t    = threadIdx.x;        // 0..511
    const int lane = t & 63;
    const int w    = t >> 6;             // 0..7
    const int row0 = blockIdx.x * NROWS;
    const int nsteps = steps_p[0];

    const float dt = 0.01f;

    // per-thread register state: v only (elements d = 2t+j); x lives in LDS.
    float vr[NROWS][2];
    const f32x2 vw = *(const f32x2*)&Vw[2 * t];

    #pragma unroll
    for (int m = 0; m < NROWS; ++m) {
        const int base = (row0 + m) * DIM + 2 * t;
        const f32x2 xv = *(const f32x2*)&x_in[base];
        const f32x2 vv = *(const f32x2*)&v_in[base];
        vr[m][0] = vv[0]; vr[m][1] = vv[1];
        *(f32x2*)&xsp[m * 1024 + 2 * t] = xv;
        const unsigned short p = (unsigned short)(f2e4m3(vv[0]) | (f2e4m3(vv[1]) << 8));
        *(unsigned short*)(smem + vs_addr(m, 2 * t)) = p;
    }
    __syncthreads();

    #pragma unroll 1
    for (int step = 0; step < nsteps; ++step) {
        #pragma unroll 1
        for (int sub = 0; sub < 4; ++sub) {
            const float cdt = dt * (sub == 0 ? (float)XI :
                                    sub == 1 ? (float)CHI :
                                    sub == 2 ? (float)(1.0 - 2.0 * (CHI + XI)) :
                                               (float)CHI);
            const float ddt = dt * ((sub == 0 || sub == 3)
                                    ? (float)((1.0 - 2.0 * LAM) * 0.5)
                                    : (float)LAM);

            // ---- drift x (LDS RMW, thread-private) + r2 reduce -> wsums ----
            #pragma unroll
            for (int m = 0; m < NROWS; ++m) {
                f32x2 x2 = *(f32x2*)&xsp[m * 1024 + 2 * t];
                x2[0] = fmaf(cdt, vr[m][0], x2[0]);
                x2[1] = fmaf(cdt, vr[m][1], x2[1]);
                *(f32x2*)&xsp[m * 1024 + 2 * t] = x2;
                float s = fmaf(x2[0], x2[0], x2[1] * x2[1]);
                #pragma unroll
                for (int off = 32; off >= 1; off >>= 1) s += __shfl_xor(s, off, 64);
                if (lane == 0) wsums[m * NWAVE + w] = s;
            }
            __syncthreads();                 // b_A: vs(v') + wsums visible
            if (t < NROWS) {
                float r2 = 0.f;
                #pragma unroll
                for (int q = 0; q < NWAVE; ++q) r2 += wsums[t * NWAVE + q];
                sings[t] = 1.f + exp2f(-r2 * 1.4426950408889634f);
            }

            // ---- H: h = v @ U (fp8); wave owns nt {2w,2w+1}; 1 load/iter ----
            // hacc = (v)·(8U) = 8h; h2 stored = e4m3(16h^2) = e4m3(hacc^2/4)
            {
                f32x4 h0 = {0.f,0.f,0.f,0.f}, h1 = {0.f,0.f,0.f,0.f};
                i64x2 bb[4];                 // ring-4 paired frags (16 VGPRs)
                #pragma unroll
                for (int d = 0; d < 4; ++d) bb[d] = pkv[(d * 8 + w) * 64 + lane];
                #pragma unroll 4
                for (int ks = 0; ks < 32; ++ks) {
                    const long a = *(const long*)(smem + vs_addr(lane & 15, ks * 32 + (lane >> 4) * 8));
                    h0 = __builtin_amdgcn_mfma_f32_16x16x32_fp8_fp8(a, bb[ks & 3][0], h0, 0, 0, 0);
                    h1 = __builtin_amdgcn_mfma_f32_16x16x32_fp8_fp8(a, bb[ks & 3][1], h1, 0, 0, 0);
                    if (ks + 4 < 32)
                        bb[ks & 3] = pkv[((ks + 4) * 8 + w) * 64 + lane];
                }
                // h2 (fp8, swizzled); D: col=lane&15, row=(lane>>4)*4+r
                #pragma unroll
                for (int r = 0; r < 4; ++r) {
                    const int m = (lane >> 4) * 4 + r;
                    const int c = lane & 15;
                    *(unsigned char*)(smem + h2_addr(m, (2 * w + 0) * 16 + c)) =
                        (unsigned char)f2e4m3(h0[r] * h0[r] * 0.25f);
                    *(unsigned char*)(smem + h2_addr(m, (2 * w + 1) * 16 + c)) =
                        (unsigned char)f2e4m3(h1[r] * h1[r] * 0.25f);
                }
            }
            __syncthreads();                 // b_B: h2 visible

            // ---- G: gamma = h2 @ W (fp8); 4 passes; 1 load/iter ----
            // gacc = (16h^2)·(8W) = 128*gamma
            {
                f32x4 g0 = {0.f,0.f,0.f,0.f}, g1 = {0.f,0.f,0.f,0.f};
                i64x2 bb[4];
                #pragma unroll
                for (int d = 0; d < 4; ++d) bb[d] = pkv[(256 + d * 8 + w) * 64 + lane];
                #pragma unroll 4
                for (int u = 0; u < 32; ++u) {
                    const int kk = u & 7;        // K-subtile
                    const int pass = u >> 3;     // n-pass
                    const long a = *(const long*)(smem + h2_addr(lane & 15, kk * 32 + (lane >> 4) * 8));
                    g0 = __builtin_amdgcn_mfma_f32_16x16x32_fp8_fp8(a, bb[u & 3][0], g0, 0, 0, 0);
                    g1 = __builtin_amdgcn_mfma_f32_16x16x32_fp8_fp8(a, bb[u & 3][1], g1, 0, 0, 0);
                    if (u + 4 < 32)
                        bb[u & 3] = pkv[(256 + (u + 4) * 8 + w) * 64 + lane];
                    if (kk == 7) {               // end of pass: gamma (fp8) -> dead vs cells
                        #pragma unroll
                        for (int r = 0; r < 4; ++r) {
                            const int m = (lane >> 4) * 4 + r;
                            const int c = lane & 15;
                            *(unsigned char*)(smem + vs_addr(m, (pass * 16 + 2 * w + 0) * 16 + c)) =
                                (unsigned char)f2e4m3(g0[r] * 0.0078125f);
                            *(unsigned char*)(smem + vs_addr(m, (pass * 16 + 2 * w + 1) * 16 + c)) =
                                (unsigned char)f2e4m3(g1[r] * 0.0078125f);
                        }
                        g0 = (f32x4){0.f,0.f,0.f,0.f};
                        g1 = (f32x4){0.f,0.f,0.f,0.f};
                    }
                }
            }
            __syncthreads();                 // b_C: gamma visible

            // ---- kick: gamma (fp8, sw decode); v' encode via HW cvt_pk ----
            #pragma unroll
            for (int m = 0; m < NROWS; ++m) {
                const f32x2 fm = *(const f32x2*)&force[(row0 + m) * DIM + 2 * t];
                const f32x2 x2 = *(const f32x2*)&xsp[m * 1024 + 2 * t];
                const unsigned gu = *(const unsigned short*)(smem + vs_addr(m, 2 * t));
                const float gL = e4m32f(gu & 0xFFu);
                const float gH = e4m32f((gu >> 8) & 0xFFu);
                const float sing = sings[m];
                #pragma unroll
                for (int j = 0; j < 2; ++j) {
                    const float g  = j ? gH : gL;
                    const float z  = x2[j] * vw[j];
                    const float e  = exp2f(z * 2.885390081777927f);   // e^(2z)
                    const float th = 1.f - 2.f / (e + 1.f);           // tanh(z)
                    const float gate = fmaf(0.1f, th, 1.f);
                    const float a = fm[j] - g * gate * sing;
                    vr[m][j] = fmaf(ddt, a, vr[m][j]);
                }
                unsigned enc;                 // HW packed fp8 encode (writes [15:0])
                asm("v_cvt_pk_fp8_f32 %0, %1, %2"
                    : "=v"(enc) : "v"(vr[m][0]), "v"(vr[m][1]));
                *(unsigned short*)(smem + vs_addr(m, 2 * t)) = (unsigned short)enc;
            }
            // next accel's b_A covers these vs writes
        } // sub

        // final drift: x += C5*dt*v  (LDS RMW, thread-private)
        const float c5dt = dt * (float)XI;
        #pragma unroll
        for (int m = 0; m < NROWS; ++m) {
            f32x2 x2 = *(f32x2*)&xsp[m * 1024 + 2 * t];
            x2[0] = fmaf(c5dt, vr[m][0], x2[0]);
            x2[1] = fmaf(c5dt, vr[m][1], x2[1]);
            *(f32x2*)&xsp[m * 1024 + 2 * t] = x2;
        }
    } // step

    __syncthreads();

    // ---- store (x, v) ----
    #pragma unroll
    for (int m = 0; m < NROWS; ++m) {
        const int base = (row0 + m) * DIM + 2 * t;
        const f32x2 x2 = *(const f32x2*)&xsp[m * 1024 + 2 * t];
        f32x2 vo; vo[0] = vr[m][0]; vo[1] = vr[m][1];
        *(f32x2*)&out[base] = x2;
        *(f32x2*)&out[OUT_HALF + base] = vo;
    }
}

extern "C" void kernel_launch(void* const* d_in, const int* in_sizes, int n_in,
                              void* d_out, int out_size, void* d_ws, size_t ws_size,
                              hipStream_t stream) {
    const float* x_in  = (const float*)d_in[0];
    const float* v_in  = (const float*)d_in[1];
    const float* force = (const float*)d_in[2];
    const float* Umat  = (const float*)d_in[3];
    const float* Wmat  = (const float*)d_in[4];
    const float* Vw    = (const float*)d_in[5];
    const int*   steps = (const int*)d_in[6];
    float* out = (float*)d_out;
    long* pk8 = (long*)d_ws;   // 512 KiB fp8 paired-fragment stream

    (void)hipFuncSetAttribute((const void*)omelyan_mfma,
                              hipFuncAttributeMaxDynamicSharedMemorySize,
                              SMEM_BYTES);

    prep_pack<<<dim3(128), dim3(256), 0, stream>>>(Umat, Wmat, pk8);
    omelyan_mfma<<<dim3(TOTAL_ROWS / NROWS), dim3(NT), SMEM_BYTES, stream>>>(
        x_in, v_in, force, Vw, steps, pk8, out);
}

// Round 28
// 276.284 us; speedup vs baseline: 1.2689x; 1.0928x over previous
//
#include <hip/hip_runtime.h>
#include <math.h>

typedef float  f32x4  __attribute__((ext_vector_type(4)));
typedef float  f32x2  __attribute__((ext_vector_type(2)));
typedef long   i64x2  __attribute__((ext_vector_type(2)));

#define DIM   1024
#define RANK  256
#define NROWS 16
#define NT    512
#define NWAVE 8
#define TOTAL_ROWS 4096
#define OUT_HALF (TOTAL_ROWS*DIM)

// LDS byte layout (119 KB) — fp8 MFMA operands, bf16 gamma, f32 x-state.
#define VS_OFF    0           // fp8[16][1024] swizzled: v / v'           (16384)
#define H2_OFF    16384       // fp8[16][256] swizzled                    (4096)
#define GS_OFF    20480       // bf16 ushort[16][1024] swizzled: gamma   (32768)
#define XS_OFF    53248       // float[16][1024] thread-private x state  (65536)
#define WS_OFF    118784      // float[16][8]
#define SG_OFF    119296      // float[16]
#define SMEM_BYTES 119360

static constexpr double XI  = 0.1786178958448091;
static constexpr double LAM = -0.2123418310626054;
static constexpr double CHI = -0.0662645826698185;

// ---- fp8 e4m3fn SOFTWARE converter — prep kernel only (cold path). Clamps. ----
__device__ __forceinline__ unsigned f2e4m3(float f) {
    unsigned u = __builtin_bit_cast(unsigned, f);
    const unsigned s = (u >> 24) & 0x80u;
    unsigned a = u & 0x7FFFFFFFu;
    const float af = __builtin_bit_cast(float, a);
    if (af < 0.015625f) {
        return s | (unsigned)(int)rintf(af * 512.0f);
    }
    a += 0x7FFFFu + ((a >> 20) & 1u);
    if (a > 0x43E00000u) return s | 0x7Eu;
    const unsigned e = (a >> 23) & 0xFFu;
    return s | ((e - 120u) << 3) | ((a >> 20) & 7u);
}

__device__ __forceinline__ unsigned short f2bf(float f) {
    unsigned u = __builtin_bit_cast(unsigned, f);
    u += 0x7FFFu + ((u >> 16) & 1u);
    return (unsigned short)(u >> 16);
}
__device__ __forceinline__ float bf2f(unsigned short b) {
    return __builtin_bit_cast(float, ((unsigned)b) << 16);
}
// HW packed fp8 encode: byte0 = e4m3(a), byte1 = e4m3(b). One VALU op.
// NOTE: does NOT saturate on overflow (no inf in e4m3fn -> emits NaN 0x7F).
// Callers must pre-clamp any input that can exceed 448 (R27's NaN bug).
__device__ __forceinline__ unsigned cvtpk_fp8(float a, float b) {
    unsigned r;
    asm("v_cvt_pk_fp8_f32 %0, %1, %2" : "=v"(r) : "v"(a), "v"(b));
    return r;
}

// swizzles
__device__ __forceinline__ int vs_addr(int m, int k) {   // fp8, 8B-granular
    return VS_OFF + ((m * 1024 + k) ^ ((m & 7) << 3));
}
__device__ __forceinline__ int h2_addr(int m, int k) {   // fp8, 8B-granular
    return H2_OFF + ((m * 256 + k) ^ ((m & 7) << 3));
}
__device__ __forceinline__ int gs_addr(int m, int kb) {  // bf16 bytes, 16B-granular
    return GS_OFF + ((m * 2048 + kb) ^ ((m & 7) << 4));
}

// ---- prep: pack 8*U, 8*W (fp8 e4m3) into PAIRED-fragment slots.
// H slot = ks*8 + w : lo=U-frag(ks, 2w), hi=U-frag(ks, 2w+1)
// G slot = 256 + (pass*8+kk)*8 + w : lo=W-frag(kk, pass*16+2w), hi=(..+1)
// frag: lane l, byte j = B[k = kt*32 + (l>>4)*8 + j][n = nt*16 + (l&15)]
__global__ __launch_bounds__(256)
void prep_pack(const float* __restrict__ U, const float* __restrict__ Wm,
               long* __restrict__ pk8)
{
    const int tid  = blockIdx.x * 256 + threadIdx.x;   // 0..32767
    const int lane = tid & 63;
    const int slot = tid >> 6;                          // 0..511
    unsigned long long lo = 0, hi = 0;
    if (slot < 256) {
        const int ks = slot >> 3, w = slot & 7;
        const int krow = ks * 32 + (lane >> 4) * 8;
        const int n0 = (2 * w + 0) * 16 + (lane & 15);
        const int n1 = (2 * w + 1) * 16 + (lane & 15);
        #pragma unroll
        for (int j = 0; j < 8; ++j) {
            lo |= (unsigned long long)f2e4m3(8.0f * U[(krow + j) * RANK + n0]) << (8 * j);
            hi |= (unsigned long long)f2e4m3(8.0f * U[(krow + j) * RANK + n1]) << (8 * j);
        }
    } else {
        const int s2 = slot - 256;
        const int u = s2 >> 3, w = s2 & 7;
        const int pass = u >> 3, kk = u & 7;
        const int krow = kk * 32 + (lane >> 4) * 8;
        const int n0 = (pass * 16 + 2 * w + 0) * 16 + (lane & 15);
        const int n1 = (pass * 16 + 2 * w + 1) * 16 + (lane & 15);
        #pragma unroll
        for (int j = 0; j < 8; ++j) {
            lo |= (unsigned long long)f2e4m3(8.0f * Wm[(krow + j) * DIM + n0]) << (8 * j);
            hi |= (unsigned long long)f2e4m3(8.0f * Wm[(krow + j) * DIM + n1]) << (8 * j);
        }
    }
    pk8[(slot * 64 + lane) * 2 + 0] = (long)lo;
    pk8[(slot * 64 + lane) * 2 + 1] = (long)hi;
}

__global__ __launch_bounds__(NT)
void omelyan_mfma(const float* __restrict__ x_in,
                  const float* __restrict__ v_in,
                  const float* __restrict__ force,
                  const float* __restrict__ Vw,
                  const int* __restrict__ steps_p,
                  const long* __restrict__ pk8,
                  float* __restrict__ out)
{
    extern __shared__ char smem[];
    float* wsums = (float*)(smem + WS_OFF);
    float* sings = (float*)(smem + SG_OFF);
    float* xsp   = (float*)(smem + XS_OFF);   // [16][1024] f32, thread-private
    const i64x2* pkv = (const i64x2*)pk8;

    const int t    = threadIdx.x;        // 0..511
    const int lane = t & 63;
    const int w    = t >> 6;             // 0..7
    const int row0 = blockIdx.x * NROWS;
    const int nsteps = steps_p[0];

    const float dt = 0.01f;

    // per-thread register state: v only (elements d = 2t+j); x lives in LDS.
    float vr[NROWS][2];
    const f32x2 vw = *(const f32x2*)&Vw[2 * t];

    #pragma unroll
    for (int m = 0; m < NROWS; ++m) {
        const int base = (row0 + m) * DIM + 2 * t;
        const f32x2 xv = *(const f32x2*)&x_in[base];
        const f32x2 vv = *(const f32x2*)&v_in[base];
        vr[m][0] = vv[0]; vr[m][1] = vv[1];
        *(f32x2*)&xsp[m * 1024 + 2 * t] = xv;
        *(unsigned short*)(smem + vs_addr(m, 2 * t)) =
            (unsigned short)cvtpk_fp8(vv[0], vv[1]);   // |v|~O(1): no overflow
    }
    __syncthreads();

    #pragma unroll 1
    for (int step = 0; step < nsteps; ++step) {
        #pragma unroll 1
        for (int sub = 0; sub < 4; ++sub) {
            const float cdt = dt * (sub == 0 ? (float)XI :
                                    sub == 1 ? (float)CHI :
                                    sub == 2 ? (float)(1.0 - 2.0 * (CHI + XI)) :
                                               (float)CHI);
            const float ddt = dt * ((sub == 0 || sub == 3)
                                    ? (float)((1.0 - 2.0 * LAM) * 0.5)
                                    : (float)LAM);

            // ---- drift x (LDS RMW, thread-private) + r2 reduce -> wsums ----
            #pragma unroll
            for (int m = 0; m < NROWS; ++m) {
                f32x2 x2 = *(f32x2*)&xsp[m * 1024 + 2 * t];
                x2[0] = fmaf(cdt, vr[m][0], x2[0]);
                x2[1] = fmaf(cdt, vr[m][1], x2[1]);
                *(f32x2*)&xsp[m * 1024 + 2 * t] = x2;
                float s = fmaf(x2[0], x2[0], x2[1] * x2[1]);
                #pragma unroll
                for (int off = 32; off >= 1; off >>= 1) s += __shfl_xor(s, off, 64);
                if (lane == 0) wsums[m * NWAVE + w] = s;
            }
            __syncthreads();                 // b_A: vs(v') + wsums visible
            if (t < NROWS) {
                float r2 = 0.f;
                #pragma unroll
                for (int q = 0; q < NWAVE; ++q) r2 += wsums[t * NWAVE + q];
                sings[t] = 1.f + exp2f(-r2 * 1.4426950408889634f);
            }

            // ---- H: h = v @ U (fp8); wave owns nt {2w,2w+1}; 1 load/iter ----
            // hacc = (v)·(8U) = 8h; h2 stored = e4m3(16h^2) = e4m3(hacc^2/4)
            {
                f32x4 h0 = {0.f,0.f,0.f,0.f}, h1 = {0.f,0.f,0.f,0.f};
                i64x2 bb[4];                 // ring-4 paired frags
                #pragma unroll
                for (int d = 0; d < 4; ++d) bb[d] = pkv[(d * 8 + w) * 64 + lane];
                #pragma unroll 4
                for (int ks = 0; ks < 32; ++ks) {
                    const long a = *(const long*)(smem + vs_addr(lane & 15, ks * 32 + (lane >> 4) * 8));
                    h0 = __builtin_amdgcn_mfma_f32_16x16x32_fp8_fp8(a, bb[ks & 3][0], h0, 0, 0, 0);
                    h1 = __builtin_amdgcn_mfma_f32_16x16x32_fp8_fp8(a, bb[ks & 3][1], h1, 0, 0, 0);
                    if (ks + 4 < 32)
                        bb[ks & 3] = pkv[((ks + 4) * 8 + w) * 64 + lane];
                }
                // h2 (fp8) via HW cvt_pk; PRE-CLAMP to 448: HW convert emits
                // NaN on e4m3 overflow (the R27 failure, ~1e-7 tail of 16h^2).
                #pragma unroll
                for (int r = 0; r < 4; ++r) {
                    const int m = (lane >> 4) * 4 + r;
                    const int c = lane & 15;
                    const float q0 = fminf(h0[r] * h0[r] * 0.25f, 448.0f);
                    const float q1 = fminf(h1[r] * h1[r] * 0.25f, 448.0f);
                    const unsigned enc = cvtpk_fp8(q0, q1);
                    *(unsigned char*)(smem + h2_addr(m, (2 * w + 0) * 16 + c)) = (unsigned char)(enc & 0xFFu);
                    *(unsigned char*)(smem + h2_addr(m, (2 * w + 1) * 16 + c)) = (unsigned char)((enc >> 8) & 0xFFu);
                }
            }
            __syncthreads();                 // b_B: h2 visible

            // ---- G: gamma = h2 @ W (fp8); 4 passes; 1 load/iter ----
            // gacc = (16h^2)·(8W) = 128*gamma; gamma stored bf16 (cheap codec)
            {
                f32x4 g0 = {0.f,0.f,0.f,0.f}, g1 = {0.f,0.f,0.f,0.f};
                i64x2 bb[4];
                #pragma unroll
                for (int d = 0; d < 4; ++d) bb[d] = pkv[(256 + d * 8 + w) * 64 + lane];
                #pragma unroll 4
                for (int u = 0; u < 32; ++u) {
                    const int kk = u & 7;        // K-subtile
                    const int pass = u >> 3;     // n-pass
                    const long a = *(const long*)(smem + h2_addr(lane & 15, kk * 32 + (lane >> 4) * 8));
                    g0 = __builtin_amdgcn_mfma_f32_16x16x32_fp8_fp8(a, bb[u & 3][0], g0, 0, 0, 0);
                    g1 = __builtin_amdgcn_mfma_f32_16x16x32_fp8_fp8(a, bb[u & 3][1], g1, 0, 0, 0);
                    if (u + 4 < 32)
                        bb[u & 3] = pkv[(256 + (u + 4) * 8 + w) * 64 + lane];
                    if (kk == 7) {               // end of pass: gamma (bf16) -> GS
                        #pragma unroll
                        for (int r = 0; r < 4; ++r) {
                            const int m = (lane >> 4) * 4 + r;
                            const int c = lane & 15;
                            *(unsigned short*)(smem + gs_addr(m, 2 * ((pass * 16 + 2 * w + 0) * 16 + c))) =
                                f2bf(g0[r] * 0.0078125f);
                            *(unsigned short*)(smem + gs_addr(m, 2 * ((pass * 16 + 2 * w + 1) * 16 + c))) =
                                f2bf(g1[r] * 0.0078125f);
                        }
                        g0 = (f32x4){0.f,0.f,0.f,0.f};
                        g1 = (f32x4){0.f,0.f,0.f,0.f};
                    }
                }
            }
            __syncthreads();                 // b_C: gamma visible

            // ---- kick: gamma bf16 from GS (1-op decode); v' via HW cvt_pk ----
            #pragma unroll
            for (int m = 0; m < NROWS; ++m) {
                const f32x2 fm = *(const f32x2*)&force[(row0 + m) * DIM + 2 * t];
                const f32x2 x2 = *(const f32x2*)&xsp[m * 1024 + 2 * t];
                const unsigned gu = *(const unsigned*)(smem + gs_addr(m, 4 * t));
                const float gL = bf2f((unsigned short)(gu & 0xFFFFu));
                const float gH = bf2f((unsigned short)(gu >> 16));
                const float sing = sings[m];
                #pragma unroll
                for (int j = 0; j < 2; ++j) {
                    const float g  = j ? gH : gL;
                    const float z  = x2[j] * vw[j];
                    const float e  = exp2f(z * 2.885390081777927f);   // e^(2z)
                    const float th = 1.f - 2.f / (e + 1.f);           // tanh(z)
                    const float gate = fmaf(0.1f, th, 1.f);
                    const float a = fm[j] - g * gate * sing;
                    vr[m][j] = fmaf(ddt, a, vr[m][j]);
                }
                *(unsigned short*)(smem + vs_addr(m, 2 * t)) =
                    (unsigned short)cvtpk_fp8(vr[m][0], vr[m][1]);   // |v|~O(1)
            }
            // next accel's b_A covers these vs writes
        } // sub

        // final drift: x += C5*dt*v  (LDS RMW, thread-private)
        const float c5dt = dt * (float)XI;
        #pragma unroll
        for (int m = 0; m < NROWS; ++m) {
            f32x2 x2 = *(f32x2*)&xsp[m * 1024 + 2 * t];
            x2[0] = fmaf(c5dt, vr[m][0], x2[0]);
            x2[1] = fmaf(c5dt, vr[m][1], x2[1]);
            *(f32x2*)&xsp[m * 1024 + 2 * t] = x2;
        }
    } // step

    __syncthreads();

    // ---- store (x, v) ----
    #pragma unroll
    for (int m = 0; m < NROWS; ++m) {
        const int base = (row0 + m) * DIM + 2 * t;
        const f32x2 x2 = *(const f32x2*)&xsp[m * 1024 + 2 * t];
        f32x2 vo; vo[0] = vr[m][0]; vo[1] = vr[m][1];
        *(f32x2*)&out[base] = x2;
        *(f32x2*)&out[OUT_HALF + base] = vo;
    }
}

extern "C" void kernel_launch(void* const* d_in, const int* in_sizes, int n_in,
                              void* d_out, int out_size, void* d_ws, size_t ws_size,
                              hipStream_t stream) {
    const float* x_in  = (const float*)d_in[0];
    const float* v_in  = (const float*)d_in[1];
    const float* force = (const float*)d_in[2];
    const float* Umat  = (const float*)d_in[3];
    const float* Wmat  = (const float*)d_in[4];
    const float* Vw    = (const float*)d_in[5];
    const int*   steps = (const int*)d_in[6];
    float* out = (float*)d_out;
    long* pk8 = (long*)d_ws;   // 512 KiB fp8 paired-fragment stream

    (void)hipFuncSetAttribute((const void*)omelyan_mfma,
                              hipFuncAttributeMaxDynamicSharedMemorySize,
                              SMEM_BYTES);

    prep_pack<<<dim3(128), dim3(256), 0, stream>>>(Umat, Wmat, pk8);
    omelyan_mfma<<<dim3(TOTAL_ROWS / NROWS), dim3(NT), SMEM_BYTES, stream>>>(
        x_in, v_in, force, Vw, steps, pk8, out);
}